// Round 1
// baseline (156.770 us; speedup 1.0000x reference)
//
#include <hip/hip_runtime.h>

typedef unsigned short USH;
typedef unsigned int   UIN;

static constexpr int Bn = 1024;    // batch
static constexpr int Hn = 200;     // history length
static constexpr int Dn = 128;     // embed/hidden
static constexpr int Dh = 64;      // half embed
static constexpr int NITEM = 50000;
static constexpr int NREG  = 1000;
static constexpr int MT = 64;      // items per ab block
static constexpr int AB_A_BLOCKS = (NITEM + MT - 1) / MT;  // 782
static constexpr int AB_B_BLOCKS = (NREG  + MT - 1) / MT;  // 16
static constexpr int AB_TOT = AB_A_BLOCKS + AB_B_BLOCKS;   // 798
static constexpr int QU_BLOCKS = Bn / 4;                   // 256 (4 rows/block)
static constexpr int G_BLOCKS  = Bn / 16;                  // 64  (16 rows/block)
static constexpr int WTS = 132;    // wt stride (floats)
static constexpr int ETS = 69;     // et stride (floats)
static constexpr int CR  = 50;     // kv rows per chunk (32*200 == 50*128)
static constexpr int AFS = 192;    // fused row: 128 kv-proj + 64 raw (bf16)

__device__ __forceinline__ float bf2f(USH u) {
  return __uint_as_float(((UIN)u) << 16);
}
__device__ __forceinline__ float2 pb2f2(UIN p) {  // packed bf16 pair -> 2 floats
  float2 r;
  r.x = __uint_as_float(p << 16);
  r.y = __uint_as_float(p & 0xffff0000u);
  return r;
}
__device__ __forceinline__ USH f2b(float f) {  // fp32 -> bf16 rne
  UIN x = __float_as_uint(f);
  return (USH)((x + 0x7fffu + ((x >> 16) & 1u)) >> 16);
}
__device__ __forceinline__ UIN addpk(UIN u, UIN v) {  // bf16x2 + bf16x2
  float2 a = pb2f2(u), b = pb2f2(v);
  return (UIN)f2b(a.x + b.x) | ((UIN)f2b(a.y + b.y) << 16);
}

// ---------------------------------------------------------------------------
// ab_kernel grid = [table GEMM | qv/uv precompute | g accumulate]
//   Af[item][0:128] = Et[item].Wk[:,0:64]^T (bf16); [128:192] = raw Et (bf16)
//   Bf[reg] likewise (Wk[:,64:128], Er).
//   qvt[i][j] = (1/sqrt128) dot(Wq[j], tgtE_i);  uvt[i][d] = sum_j Wv[j][d] tgtE_i[j]
//   g[c] += sum_i row[tr[i]]*row[hr[i,c]]  (row = embed_dist[uid]; g pre-zeroed)
// ---------------------------------------------------------------------------
__global__ __launch_bounds__(256, 2) void ab_kernel(
    const float* __restrict__ Et, const float* __restrict__ Er,
    const float* __restrict__ Wk, const float* __restrict__ Wq,
    const float* __restrict__ Wv, const int* __restrict__ target,
    const int* __restrict__ tregion, const int* __restrict__ hregion,
    const float* __restrict__ embed_dist, const int* __restrict__ uid,
    USH* __restrict__ Af, USH* __restrict__ Bf,
    float* __restrict__ qvt, float* __restrict__ uvt, float* __restrict__ g) {
  __shared__ float wt[64 * WTS];  // 33.8KB (qu path reuses as te[4][128])
  __shared__ float et[MT * ETS];  // 17.7KB
  int blk = blockIdx.x, tid = threadIdx.x;

  if (blk >= AB_TOT + QU_BLOCKS) {
    // ---------------- g-accumulate path (64 blocks x 16 rows) ----------------
    int c = tid;
    const float* row = embed_dist + (size_t)uid[0] * NREG;  // 4KB, L1-resident
    float acc = 0.f;
    int ibase = (blk - AB_TOT - QU_BLOCKS) * 16;
    for (int ii = 0; ii < 16; ii++) {
      int i = ibase + ii;
      float td = row[tregion[i]];             // wave-uniform broadcast
      if (c < Hn) acc += td * row[hregion[(size_t)i * Hn + c]];
    }
    if (c < Hn) atomicAdd(&g[c], acc);
    return;
  }

  if (blk >= AB_TOT) {
    // ---------------- qv/uv precompute path ----------------
    float* te = wt;  // te[ii*128 + d], 4 target-embed rows
    int i0 = (blk - AB_TOT) * 4;
#pragma unroll
    for (int v = 0; v < 2; v++) {
      int idx = v * 256 + tid;      // 0..511
      int ii = idx >> 7, d = idx & 127;
      int it = i0 + ii;
      te[ii * 128 + d] = (d < 64) ? Et[(size_t)target[it] * Dh + d]
                                  : Er[(size_t)tregion[it] * Dh + (d - 64)];
    }
    __syncthreads();
    int j = tid & 127, half = tid >> 7;
    float a0 = 0.f, a1 = 0.f, a2 = 0.f, a3 = 0.f;
    if (half == 0) {  // qv: thread j owns Wq row j, 4 batch rows at once
      const float* wr = Wq + (size_t)j * Dn;
#pragma unroll 8
      for (int k = 0; k < 128; k++) {
        float w = wr[k];
        a0 += w * te[k]; a1 += w * te[128 + k];
        a2 += w * te[256 + k]; a3 += w * te[384 + k];
      }
      const float s = 0.088388347648318447f;  // 1/sqrt(128)
      qvt[(size_t)(i0 + 0) * Dn + j] = a0 * s;
      qvt[(size_t)(i0 + 1) * Dn + j] = a1 * s;
      qvt[(size_t)(i0 + 2) * Dn + j] = a2 * s;
      qvt[(size_t)(i0 + 3) * Dn + j] = a3 * s;
    } else {          // uv: column sweep, coalesced across d
      int d = j;
#pragma unroll 8
      for (int k = 0; k < 128; k++) {
        float w = Wv[(size_t)k * Dn + d];
        a0 += w * te[k]; a1 += w * te[128 + k];
        a2 += w * te[256 + k]; a3 += w * te[384 + k];
      }
      uvt[(size_t)(i0 + 0) * Dn + d] = a0;
      uvt[(size_t)(i0 + 1) * Dn + d] = a1;
      uvt[(size_t)(i0 + 2) * Dn + d] = a2;
      uvt[(size_t)(i0 + 3) * Dn + d] = a3;
    }
    return;
  }

  // ---------------- fused-table GEMM path ----------------
  const float* E; USH* Out; int nmax, base, koff;
  if (blk < AB_A_BLOCKS) { E = Et; Out = Af; nmax = NITEM; base = blk * MT; koff = 0; }
  else { E = Er; Out = Bf; nmax = NREG; base = (blk - AB_A_BLOCKS) * MT; koff = 64; }

  // stage Wk transposed
#pragma unroll
  for (int p = 0; p < 8; p++) {
    int idx = p * 256 + tid;
    int row = idx >> 4, c4 = idx & 15;
    float4 w = *reinterpret_cast<const float4*>(Wk + (size_t)row * Dn + koff + c4 * 4);
    wt[(c4 * 4 + 0) * WTS + row] = w.x;
    wt[(c4 * 4 + 1) * WTS + row] = w.y;
    wt[(c4 * 4 + 2) * WTS + row] = w.z;
    wt[(c4 * 4 + 3) * WTS + row] = w.w;
  }
  // stage E rows row-major
#pragma unroll
  for (int p = 0; p < 4; p++) {
    int idx = p * 256 + tid;
    int m = idx >> 4, c4 = idx & 15;
    int gi = base + m;
    float4 e = make_float4(0.f, 0.f, 0.f, 0.f);
    if (gi < nmax) e = *reinterpret_cast<const float4*>(E + (size_t)gi * Dh + c4 * 4);
    et[m * ETS + c4 * 4 + 0] = e.x;
    et[m * ETS + c4 * 4 + 1] = e.y;
    et[m * ETS + c4 * 4 + 2] = e.z;
    et[m * ETS + c4 * 4 + 3] = e.w;
  }
  __syncthreads();

  // raw-half emit: Out[item][128 + 2kp ..] = bf16(E row)
#pragma unroll
  for (int q = 0; q < 8; q++) {
    int idx = q * 256 + tid;       // 0..2047
    int m = idx >> 5, kp = idx & 31;
    int gi = base + m;
    if (gi < nmax) {
      UIN pk = (UIN)f2b(et[m * ETS + 2 * kp]) | ((UIN)f2b(et[m * ETS + 2 * kp + 1]) << 16);
      *reinterpret_cast<UIN*>(Out + (size_t)gi * AFS + 128 + 2 * kp) = pk;
    }
  }

  int jt = tid & 15, it = tid >> 4;     // 8 j's, 4 items per thread
  const float* wb = wt + jt * 8;
  const float* eb = et + (it * 4) * ETS;
  float c[4][8];
#pragma unroll
  for (int ii = 0; ii < 4; ii++)
#pragma unroll
    for (int jj = 0; jj < 8; jj++) c[ii][jj] = 0.f;

#pragma unroll 2
  for (int k = 0; k < 64; k++) {
    float4 w0 = *reinterpret_cast<const float4*>(wb + (size_t)k * WTS);
    float4 w1 = *reinterpret_cast<const float4*>(wb + (size_t)k * WTS + 4);
    float e0 = eb[k], e1 = eb[ETS + k], e2 = eb[2 * ETS + k], e3 = eb[3 * ETS + k];
    c[0][0] += e0 * w0.x; c[0][1] += e0 * w0.y; c[0][2] += e0 * w0.z; c[0][3] += e0 * w0.w;
    c[0][4] += e0 * w1.x; c[0][5] += e0 * w1.y; c[0][6] += e0 * w1.z; c[0][7] += e0 * w1.w;
    c[1][0] += e1 * w0.x; c[1][1] += e1 * w0.y; c[1][2] += e1 * w0.z; c[1][3] += e1 * w0.w;
    c[1][4] += e1 * w1.x; c[1][5] += e1 * w1.y; c[1][6] += e1 * w1.z; c[1][7] += e1 * w1.w;
    c[2][0] += e2 * w0.x; c[2][1] += e2 * w0.y; c[2][2] += e2 * w0.z; c[2][3] += e2 * w0.w;
    c[2][4] += e2 * w1.x; c[2][5] += e2 * w1.y; c[2][6] += e2 * w1.z; c[2][7] += e2 * w1.w;
    c[3][0] += e3 * w0.x; c[3][1] += e3 * w0.y; c[3][2] += e3 * w0.z; c[3][3] += e3 * w0.w;
    c[3][4] += e3 * w1.x; c[3][5] += e3 * w1.y; c[3][6] += e3 * w1.z; c[3][7] += e3 * w1.w;
  }

#pragma unroll
  for (int ii = 0; ii < 4; ii++) {
    int item = base + it * 4 + ii;
    if (item < nmax) {
      uint4 pk;
      pk.x = (UIN)f2b(c[ii][0]) | ((UIN)f2b(c[ii][1]) << 16);
      pk.y = (UIN)f2b(c[ii][2]) | ((UIN)f2b(c[ii][3]) << 16);
      pk.z = (UIN)f2b(c[ii][4]) | ((UIN)f2b(c[ii][5]) << 16);
      pk.w = (UIN)f2b(c[ii][6]) | ((UIN)f2b(c[ii][7]) << 16);
      *reinterpret_cast<uint4*>(Out + (size_t)item * AFS + jt * 8) = pk;
    }
  }
}

// ---------------------------------------------------------------------------
// Partial scores + s1/s2: 4096 blocks = (batch i) x (chunk h of 4).
// v12: raw-half uint4s PREFETCHED into registers before the barrier, so all
// gather loads (kv staging + raw) are in flight concurrently; dots run
// post-barrier from registers. Same bytes, deeper MLP.
// ---------------------------------------------------------------------------
__global__ __launch_bounds__(256, 4) void sc_kernel(
    const int* __restrict__ history, const int* __restrict__ target,
    const int* __restrict__ hregion, const int* __restrict__ tregion,
    const float* __restrict__ Et, const float* __restrict__ Er,
    const float* __restrict__ qvt, const float* __restrict__ uvt,
    const USH* __restrict__ Af, const USH* __restrict__ Bf,
    float* __restrict__ psc, float2* __restrict__ s12) {
  __shared__ USH kvs[CR * Dn];      // 12800B
  __shared__ float tgtE[128], uvf[128], qv[32];
  int b = blockIdx.x, i = b >> 2, h = b & 3;
  int tid = threadIdx.x;
  const int* hrow = history + (size_t)i * Hn + CR * h;
  const int* rrow = hregion + (size_t)i * Hn + CR * h;

  if (tid < 128) {
    tgtE[tid] = (tid < 64) ? Et[(size_t)target[i] * Dh + tid]
                           : Er[(size_t)tregion[i] * Dh + (tid - 64)];
  } else {
    uvf[tid - 128] = uvt[(size_t)i * Dn + (tid - 128)];
  }
  if (tid < 32) qv[tid] = qvt[(size_t)i * Dn + 32 * h + tid];

  // stage kv halves: 16 lanes x 16B per row
  {
    int rlane = tid & 15, rgrp = tid >> 4;
#pragma unroll
    for (int p = 0; p < 4; p++) {
      int t = p * 16 + rgrp;
      if (t < CR) {
        int ia = hrow[t], ib = rrow[t];
        uint4 av = *reinterpret_cast<const uint4*>(Af + (size_t)ia * AFS + rlane * 8);
        uint4 bv = *reinterpret_cast<const uint4*>(Bf + (size_t)ib * AFS + rlane * 8);
        uint4 pk;
        pk.x = addpk(av.x, bv.x); pk.y = addpk(av.y, bv.y);
        pk.z = addpk(av.z, bv.z); pk.w = addpk(av.w, bv.w);
        *reinterpret_cast<uint4*>(&kvs[t * Dn + rlane * 8]) = pk;
      }
    }
  }

  // prefetch raw halves into registers (no LDS dependency -> before barrier)
  int l8 = tid & 7, r8 = tid >> 3;     // 8 lanes/row, rows r8 and 32+r8
  int ta = r8, tb = 32 + r8;
  bool hasb = (tb < CR);
  uint4 ea, ra, eb2, rb2;
  {
    int iaa = hrow[ta], iba = rrow[ta];
    ea = *reinterpret_cast<const uint4*>(Af + (size_t)iaa * AFS + 128 + l8 * 8);
    ra = *reinterpret_cast<const uint4*>(Bf + (size_t)iba * AFS + 128 + l8 * 8);
    if (hasb) {
      int iab = hrow[tb], ibb = rrow[tb];
      eb2 = *reinterpret_cast<const uint4*>(Af + (size_t)iab * AFS + 128 + l8 * 8);
      rb2 = *reinterpret_cast<const uint4*>(Bf + (size_t)ibb * AFS + 128 + l8 * 8);
    }
  }
  __syncthreads();  // kvs + tgtE/uvf/qv ready

  // raw dots from prefetched registers
#pragma unroll
  for (int pass = 0; pass < 2; pass++) {
    if (pass == 1 && !hasb) break;
    uint4 e = (pass == 0) ? ea : eb2;
    uint4 r = (pass == 0) ? ra : rb2;
    int t = (pass == 0) ? ta : tb;
    float2 e0 = pb2f2(e.x), e1 = pb2f2(e.y), e2 = pb2f2(e.z), e3 = pb2f2(e.w);
    float2 r0 = pb2f2(r.x), r1 = pb2f2(r.y), r2 = pb2f2(r.z), r3 = pb2f2(r.w);
    const float* u0 = &uvf[l8 * 8];       const float* t0 = &tgtE[l8 * 8];
    const float* u1 = &uvf[64 + l8 * 8];  const float* t1 = &tgtE[64 + l8 * 8];
    float s1a = e0.x * u0[0] + e0.y * u0[1] + e1.x * u0[2] + e1.y * u0[3]
              + e2.x * u0[4] + e2.y * u0[5] + e3.x * u0[6] + e3.y * u0[7]
              + r0.x * u1[0] + r0.y * u1[1] + r1.x * u1[2] + r1.y * u1[3]
              + r2.x * u1[4] + r2.y * u1[5] + r3.x * u1[6] + r3.y * u1[7];
    float s2a = e0.x * t0[0] + e0.y * t0[1] + e1.x * t0[2] + e1.y * t0[3]
              + e2.x * t0[4] + e2.y * t0[5] + e3.x * t0[6] + e3.y * t0[7]
              + r0.x * t1[0] + r0.y * t1[1] + r1.x * t1[2] + r1.y * t1[3]
              + r2.x * t1[4] + r2.y * t1[5] + r3.x * t1[6] + r3.y * t1[7];
    s1a += __shfl_xor(s1a, 1, 64); s2a += __shfl_xor(s2a, 1, 64);
    s1a += __shfl_xor(s1a, 2, 64); s2a += __shfl_xor(s2a, 2, 64);
    s1a += __shfl_xor(s1a, 4, 64); s2a += __shfl_xor(s2a, 4, 64);
    if (l8 == 0) s12[(size_t)i * Hn + CR * h + t] = make_float2(s1a, s2a);
  }

  // scores: buffer halfword index a'*200 + c (zero address math)
  if (tid < Hn) {
    float acc = 0.f;
    const USH* kp = &kvs[tid];
#pragma unroll
    for (int a = 0; a < 32; a++) acc += qv[a] * bf2f(kp[a * 200]);
    psc[((size_t)i * 4 + h) * Hn + tid] = acc;
  }
}

// ---------------------------------------------------------------------------
// Epilogue: one block per batch row. Fully coalesced — no gathers.
// ---------------------------------------------------------------------------
__global__ __launch_bounds__(256, 8) void ep_kernel(
    const int* __restrict__ history, const int* __restrict__ target,
    const float* __restrict__ hv, const float* __restrict__ dist_mat,
    const float* __restrict__ g, const float* __restrict__ psc,
    const float2* __restrict__ s12, float* __restrict__ out) {
  __shared__ float red[8];
  int i = blockIdx.x, tid = threadIdx.x, lane = tid & 63, wave = tid >> 6;
  int tgt_i = target[i];

  float ea = 0.f; float2 sv = make_float2(0.f, 0.f);
  if (tid < Hn) {
    const float* pp = psc + (size_t)i * 4 * Hn + tid;
    float s = (pp[0] + pp[Hn]) + (pp[2 * Hn] + pp[3 * Hn]);
    sv = s12[(size_t)i * Hn + tid];
    ea = (history[(size_t)i * Hn + tid] != tgt_i) ? __expf(s) : 0.f;
  }
  float wsum = ea;
  for (int off = 32; off > 0; off >>= 1) wsum += __shfl_down(wsum, off, 64);
  if (lane == 0) red[wave] = wsum;
  __syncthreads();
  float esum = red[0] + red[1] + red[2] + red[3];
  float inv = esum > 0.f ? 1.f / sqrtf(esum) : 0.f;  // exp_sum ** 0.5 (BETA)

  float part = 0.f;
  if (tid < Hn) {
    float gc = g[tid]; gc = gc > 0.f ? gc : 0.f;  // relu
    float dm = dist_mat[(size_t)i * Hn + tid];
    float geo = __expf(-dm / (gc + 1.f));
    part = (ea * inv + geo) * sv.x + hv[tid] * sv.y;
  }
  __syncthreads();  // protect red[] reuse
  for (int off = 32; off > 0; off >>= 1) part += __shfl_down(part, off, 64);
  if (lane == 0) red[wave] = part;
  __syncthreads();
  if (tid == 0) {
    float pred = red[0] + red[1] + red[2] + red[3];
    out[i] = 1.f / (1.f + __expf(-pred));
  }
}

extern "C" void kernel_launch(void* const* d_in, const int* in_sizes, int n_in,
                              void* d_out, int out_size, void* d_ws, size_t ws_size,
                              hipStream_t stream) {
  const int*   history = (const int*)d_in[0];
  const int*   target  = (const int*)d_in[1];
  const int*   hregion = (const int*)d_in[2];
  const int*   tregion = (const int*)d_in[3];
  const float* hv      = (const float*)d_in[4];
  const float* dist    = (const float*)d_in[5];
  const int*   uid     = (const int*)d_in[6];
  const float* Et      = (const float*)d_in[7];
  const float* Er      = (const float*)d_in[8];
  const float* Edist   = (const float*)d_in[9];
  const float* Wq      = (const float*)d_in[10];
  const float* Wk      = (const float*)d_in[11];
  const float* Wv      = (const float*)d_in[12];

  char* w = (char*)d_ws;
  float* g   = (float*)w;                            // 1KB slot
  USH*   Af  = (USH*)(w + 1024);                     // 50000*192 bf16 = 19.2MB
  USH*   Bf  = Af + (size_t)NITEM * AFS;             // 1000*192 bf16 = 384KB
  float* qvt = (float*)(Bf + (size_t)NREG * AFS);    // 1024*128 f32 = 512KB
  float* uvt = qvt + (size_t)Bn * Dn;                // 512KB
  float* psc = uvt + (size_t)Bn * Dn;                // 1024*4*200 f32 = 3.2MB
  float2* s12 = (float2*)(psc + (size_t)Bn * 4 * Hn);// 1024*200 float2 = 1.6MB
  float* out = (float*)d_out;

  hipMemsetAsync(g, 0, Hn * sizeof(float), stream);
  ab_kernel<<<AB_TOT + QU_BLOCKS + G_BLOCKS, 256, 0, stream>>>(
      Et, Er, Wk, Wq, Wv, target, tregion, hregion, Edist, uid,
      Af, Bf, qvt, uvt, g);
  sc_kernel<<<Bn * 4, 256, 0, stream>>>(history, target, hregion, tregion,
                                        Et, Er, qvt, uvt, Af, Bf, psc, s12);
  ep_kernel<<<Bn, 256, 0, stream>>>(history, target, hv, dist, g, psc, s12, out);
}

// Round 2
// 156.499 us; speedup vs baseline: 1.0017x; 1.0017x over previous
//
#include <hip/hip_runtime.h>

typedef unsigned short USH;
typedef unsigned int   UIN;

static constexpr int Bn = 1024;    // batch
static constexpr int Hn = 200;     // history length
static constexpr int Dn = 128;     // embed/hidden
static constexpr int Dh = 64;      // half embed
static constexpr int NITEM = 50000;
static constexpr int NREG  = 1000;
static constexpr int MT = 64;      // items per ab block
static constexpr int AB_A_BLOCKS = (NITEM + MT - 1) / MT;  // 782
static constexpr int AB_B_BLOCKS = (NREG  + MT - 1) / MT;  // 16
static constexpr int AB_TOT = AB_A_BLOCKS + AB_B_BLOCKS;   // 798
static constexpr int QU_BLOCKS = Bn / 4;                   // 256 (4 rows/block)
static constexpr int G_BLOCKS  = Bn / 16;                  // 64  (16 rows/block)
static constexpr int WTS = 132;    // wt stride (floats)
static constexpr int ETS = 69;     // et stride (floats)
static constexpr int CR  = 50;     // kv rows per chunk (32*200 == 50*128)
static constexpr int AFS = 192;    // fused row: 128 kv-proj + 64 raw (bf16)

__device__ __forceinline__ float bf2f(USH u) {
  return __uint_as_float(((UIN)u) << 16);
}
__device__ __forceinline__ float2 pb2f2(UIN p) {  // packed bf16 pair -> 2 floats
  float2 r;
  r.x = __uint_as_float(p << 16);
  r.y = __uint_as_float(p & 0xffff0000u);
  return r;
}
__device__ __forceinline__ USH f2b(float f) {  // fp32 -> bf16 rne
  UIN x = __float_as_uint(f);
  return (USH)((x + 0x7fffu + ((x >> 16) & 1u)) >> 16);
}
__device__ __forceinline__ UIN addpk(UIN u, UIN v) {  // bf16x2 + bf16x2
  float2 a = pb2f2(u), b = pb2f2(v);
  return (UIN)f2b(a.x + b.x) | ((UIN)f2b(a.y + b.y) << 16);
}

// ---------------------------------------------------------------------------
// ab_kernel grid = [table GEMM | qv/uv precompute | g accumulate]
//   Af[item][0:128] = Et[item].Wk[:,0:64]^T (bf16); [128:192] = raw Et (bf16)
//   Bf[reg] likewise (Wk[:,64:128], Er).
//   qvt[i][j] = (1/sqrt128) dot(Wq[j], tgtE_i);  uvt[i][d] = sum_j Wv[j][d] tgtE_i[j]
//   g[c] += sum_i row[tr[i]]*row[hr[i,c]]  (row = embed_dist[uid]; g pre-zeroed)
// ---------------------------------------------------------------------------
__global__ __launch_bounds__(256, 2) void ab_kernel(
    const float* __restrict__ Et, const float* __restrict__ Er,
    const float* __restrict__ Wk, const float* __restrict__ Wq,
    const float* __restrict__ Wv, const int* __restrict__ target,
    const int* __restrict__ tregion, const int* __restrict__ hregion,
    const float* __restrict__ embed_dist, const int* __restrict__ uid,
    USH* __restrict__ Af, USH* __restrict__ Bf,
    float* __restrict__ qvt, float* __restrict__ uvt, float* __restrict__ g) {
  __shared__ float wt[64 * WTS];  // 33.8KB (qu path reuses as te[4][128])
  __shared__ float et[MT * ETS];  // 17.7KB
  int blk = blockIdx.x, tid = threadIdx.x;

  if (blk >= AB_TOT + QU_BLOCKS) {
    // ---------------- g-accumulate path (64 blocks x 16 rows) ----------------
    int c = tid;
    const float* row = embed_dist + (size_t)uid[0] * NREG;  // 4KB, L1-resident
    float acc = 0.f;
    int ibase = (blk - AB_TOT - QU_BLOCKS) * 16;
    for (int ii = 0; ii < 16; ii++) {
      int i = ibase + ii;
      float td = row[tregion[i]];             // wave-uniform broadcast
      if (c < Hn) acc += td * row[hregion[(size_t)i * Hn + c]];
    }
    if (c < Hn) atomicAdd(&g[c], acc);
    return;
  }

  if (blk >= AB_TOT) {
    // ---------------- qv/uv precompute path ----------------
    float* te = wt;  // te[ii*128 + d], 4 target-embed rows
    int i0 = (blk - AB_TOT) * 4;
#pragma unroll
    for (int v = 0; v < 2; v++) {
      int idx = v * 256 + tid;      // 0..511
      int ii = idx >> 7, d = idx & 127;
      int it = i0 + ii;
      te[ii * 128 + d] = (d < 64) ? Et[(size_t)target[it] * Dh + d]
                                  : Er[(size_t)tregion[it] * Dh + (d - 64)];
    }
    __syncthreads();
    int j = tid & 127, half = tid >> 7;
    float a0 = 0.f, a1 = 0.f, a2 = 0.f, a3 = 0.f;
    if (half == 0) {  // qv: thread j owns Wq row j, 4 batch rows at once
      const float* wr = Wq + (size_t)j * Dn;
#pragma unroll 8
      for (int k = 0; k < 128; k++) {
        float w = wr[k];
        a0 += w * te[k]; a1 += w * te[128 + k];
        a2 += w * te[256 + k]; a3 += w * te[384 + k];
      }
      const float s = 0.088388347648318447f;  // 1/sqrt(128)
      qvt[(size_t)(i0 + 0) * Dn + j] = a0 * s;
      qvt[(size_t)(i0 + 1) * Dn + j] = a1 * s;
      qvt[(size_t)(i0 + 2) * Dn + j] = a2 * s;
      qvt[(size_t)(i0 + 3) * Dn + j] = a3 * s;
    } else {          // uv: column sweep, coalesced across d
      int d = j;
#pragma unroll 8
      for (int k = 0; k < 128; k++) {
        float w = Wv[(size_t)k * Dn + d];
        a0 += w * te[k]; a1 += w * te[128 + k];
        a2 += w * te[256 + k]; a3 += w * te[384 + k];
      }
      uvt[(size_t)(i0 + 0) * Dn + d] = a0;
      uvt[(size_t)(i0 + 1) * Dn + d] = a1;
      uvt[(size_t)(i0 + 2) * Dn + d] = a2;
      uvt[(size_t)(i0 + 3) * Dn + d] = a3;
    }
    return;
  }

  // ---------------- fused-table GEMM path ----------------
  const float* E; USH* Out; int nmax, base, koff;
  if (blk < AB_A_BLOCKS) { E = Et; Out = Af; nmax = NITEM; base = blk * MT; koff = 0; }
  else { E = Er; Out = Bf; nmax = NREG; base = (blk - AB_A_BLOCKS) * MT; koff = 64; }

  // stage Wk transposed
#pragma unroll
  for (int p = 0; p < 8; p++) {
    int idx = p * 256 + tid;
    int row = idx >> 4, c4 = idx & 15;
    float4 w = *reinterpret_cast<const float4*>(Wk + (size_t)row * Dn + koff + c4 * 4);
    wt[(c4 * 4 + 0) * WTS + row] = w.x;
    wt[(c4 * 4 + 1) * WTS + row] = w.y;
    wt[(c4 * 4 + 2) * WTS + row] = w.z;
    wt[(c4 * 4 + 3) * WTS + row] = w.w;
  }
  // stage E rows row-major
#pragma unroll
  for (int p = 0; p < 4; p++) {
    int idx = p * 256 + tid;
    int m = idx >> 4, c4 = idx & 15;
    int gi = base + m;
    float4 e = make_float4(0.f, 0.f, 0.f, 0.f);
    if (gi < nmax) e = *reinterpret_cast<const float4*>(E + (size_t)gi * Dh + c4 * 4);
    et[m * ETS + c4 * 4 + 0] = e.x;
    et[m * ETS + c4 * 4 + 1] = e.y;
    et[m * ETS + c4 * 4 + 2] = e.z;
    et[m * ETS + c4 * 4 + 3] = e.w;
  }
  __syncthreads();

  // raw-half emit: Out[item][128 + 2kp ..] = bf16(E row)
#pragma unroll
  for (int q = 0; q < 8; q++) {
    int idx = q * 256 + tid;       // 0..2047
    int m = idx >> 5, kp = idx & 31;
    int gi = base + m;
    if (gi < nmax) {
      UIN pk = (UIN)f2b(et[m * ETS + 2 * kp]) | ((UIN)f2b(et[m * ETS + 2 * kp + 1]) << 16);
      *reinterpret_cast<UIN*>(Out + (size_t)gi * AFS + 128 + 2 * kp) = pk;
    }
  }

  int jt = tid & 15, it = tid >> 4;     // 8 j's, 4 items per thread
  const float* wb = wt + jt * 8;
  const float* eb = et + (it * 4) * ETS;
  float c[4][8];
#pragma unroll
  for (int ii = 0; ii < 4; ii++)
#pragma unroll
    for (int jj = 0; jj < 8; jj++) c[ii][jj] = 0.f;

#pragma unroll 2
  for (int k = 0; k < 64; k++) {
    float4 w0 = *reinterpret_cast<const float4*>(wb + (size_t)k * WTS);
    float4 w1 = *reinterpret_cast<const float4*>(wb + (size_t)k * WTS + 4);
    float e0 = eb[k], e1 = eb[ETS + k], e2 = eb[2 * ETS + k], e3 = eb[3 * ETS + k];
    c[0][0] += e0 * w0.x; c[0][1] += e0 * w0.y; c[0][2] += e0 * w0.z; c[0][3] += e0 * w0.w;
    c[0][4] += e0 * w1.x; c[0][5] += e0 * w1.y; c[0][6] += e0 * w1.z; c[0][7] += e0 * w1.w;
    c[1][0] += e1 * w0.x; c[1][1] += e1 * w0.y; c[1][2] += e1 * w0.z; c[1][3] += e1 * w0.w;
    c[1][4] += e1 * w1.x; c[1][5] += e1 * w1.y; c[1][6] += e1 * w1.z; c[1][7] += e1 * w1.w;
    c[2][0] += e2 * w0.x; c[2][1] += e2 * w0.y; c[2][2] += e2 * w0.z; c[2][3] += e2 * w0.w;
    c[2][4] += e2 * w1.x; c[2][5] += e2 * w1.y; c[2][6] += e2 * w1.z; c[2][7] += e2 * w1.w;
    c[3][0] += e3 * w0.x; c[3][1] += e3 * w0.y; c[3][2] += e3 * w0.z; c[3][3] += e3 * w0.w;
    c[3][4] += e3 * w1.x; c[3][5] += e3 * w1.y; c[3][6] += e3 * w1.z; c[3][7] += e3 * w1.w;
  }

#pragma unroll
  for (int ii = 0; ii < 4; ii++) {
    int item = base + it * 4 + ii;
    if (item < nmax) {
      uint4 pk;
      pk.x = (UIN)f2b(c[ii][0]) | ((UIN)f2b(c[ii][1]) << 16);
      pk.y = (UIN)f2b(c[ii][2]) | ((UIN)f2b(c[ii][3]) << 16);
      pk.z = (UIN)f2b(c[ii][4]) | ((UIN)f2b(c[ii][5]) << 16);
      pk.w = (UIN)f2b(c[ii][6]) | ((UIN)f2b(c[ii][7]) << 16);
      *reinterpret_cast<uint4*>(Out + (size_t)item * AFS + jt * 8) = pk;
    }
  }
}

// ---------------------------------------------------------------------------
// Partial scores + s1/s2: 4096 blocks = (batch i) x (chunk h of 4).
// v13: occupancy 4 -> 6 blocks/CU (16 -> 24 waves/CU). Theory: gather-latency
// bound (random 16B loads into 19.6MB Af, ~700cy L3 round-trip); +50% resident
// waves = +50% outstanding loads. LDS 13.9KB*6 = 83KB ok; VGPR cap ~84.
// ---------------------------------------------------------------------------
__global__ __launch_bounds__(256, 6) void sc_kernel(
    const int* __restrict__ history, const int* __restrict__ target,
    const int* __restrict__ hregion, const int* __restrict__ tregion,
    const float* __restrict__ Et, const float* __restrict__ Er,
    const float* __restrict__ qvt, const float* __restrict__ uvt,
    const USH* __restrict__ Af, const USH* __restrict__ Bf,
    float* __restrict__ psc, float2* __restrict__ s12) {
  __shared__ USH kvs[CR * Dn];      // 12800B
  __shared__ float tgtE[128], uvf[128], qv[32];
  int b = blockIdx.x, i = b >> 2, h = b & 3;
  int tid = threadIdx.x;
  const int* hrow = history + (size_t)i * Hn + CR * h;
  const int* rrow = hregion + (size_t)i * Hn + CR * h;

  if (tid < 128) {
    tgtE[tid] = (tid < 64) ? Et[(size_t)target[i] * Dh + tid]
                           : Er[(size_t)tregion[i] * Dh + (tid - 64)];
  } else {
    uvf[tid - 128] = uvt[(size_t)i * Dn + (tid - 128)];
  }
  if (tid < 32) qv[tid] = qvt[(size_t)i * Dn + 32 * h + tid];

  // stage kv halves: 16 lanes x 16B per row
  {
    int rlane = tid & 15, rgrp = tid >> 4;
#pragma unroll
    for (int p = 0; p < 4; p++) {
      int t = p * 16 + rgrp;
      if (t < CR) {
        int ia = hrow[t], ib = rrow[t];
        uint4 av = *reinterpret_cast<const uint4*>(Af + (size_t)ia * AFS + rlane * 8);
        uint4 bv = *reinterpret_cast<const uint4*>(Bf + (size_t)ib * AFS + rlane * 8);
        uint4 pk;
        pk.x = addpk(av.x, bv.x); pk.y = addpk(av.y, bv.y);
        pk.z = addpk(av.z, bv.z); pk.w = addpk(av.w, bv.w);
        *reinterpret_cast<uint4*>(&kvs[t * Dn + rlane * 8]) = pk;
      }
    }
  }

  // prefetch raw halves into registers (no LDS dependency -> before barrier)
  int l8 = tid & 7, r8 = tid >> 3;     // 8 lanes/row, rows r8 and 32+r8
  int ta = r8, tb = 32 + r8;
  bool hasb = (tb < CR);
  uint4 ea, ra, eb2, rb2;
  {
    int iaa = hrow[ta], iba = rrow[ta];
    ea = *reinterpret_cast<const uint4*>(Af + (size_t)iaa * AFS + 128 + l8 * 8);
    ra = *reinterpret_cast<const uint4*>(Bf + (size_t)iba * AFS + 128 + l8 * 8);
    if (hasb) {
      int iab = hrow[tb], ibb = rrow[tb];
      eb2 = *reinterpret_cast<const uint4*>(Af + (size_t)iab * AFS + 128 + l8 * 8);
      rb2 = *reinterpret_cast<const uint4*>(Bf + (size_t)ibb * AFS + 128 + l8 * 8);
    }
  }
  __syncthreads();  // kvs + tgtE/uvf/qv ready

  // raw dots from prefetched registers
#pragma unroll
  for (int pass = 0; pass < 2; pass++) {
    if (pass == 1 && !hasb) break;
    uint4 e = (pass == 0) ? ea : eb2;
    uint4 r = (pass == 0) ? ra : rb2;
    int t = (pass == 0) ? ta : tb;
    float2 e0 = pb2f2(e.x), e1 = pb2f2(e.y), e2 = pb2f2(e.z), e3 = pb2f2(e.w);
    float2 r0 = pb2f2(r.x), r1 = pb2f2(r.y), r2 = pb2f2(r.z), r3 = pb2f2(r.w);
    const float* u0 = &uvf[l8 * 8];       const float* t0 = &tgtE[l8 * 8];
    const float* u1 = &uvf[64 + l8 * 8];  const float* t1 = &tgtE[64 + l8 * 8];
    float s1a = e0.x * u0[0] + e0.y * u0[1] + e1.x * u0[2] + e1.y * u0[3]
              + e2.x * u0[4] + e2.y * u0[5] + e3.x * u0[6] + e3.y * u0[7]
              + r0.x * u1[0] + r0.y * u1[1] + r1.x * u1[2] + r1.y * u1[3]
              + r2.x * u1[4] + r2.y * u1[5] + r3.x * u1[6] + r3.y * u1[7];
    float s2a = e0.x * t0[0] + e0.y * t0[1] + e1.x * t0[2] + e1.y * t0[3]
              + e2.x * t0[4] + e2.y * t0[5] + e3.x * t0[6] + e3.y * t0[7]
              + r0.x * t1[0] + r0.y * t1[1] + r1.x * t1[2] + r1.y * t1[3]
              + r2.x * t1[4] + r2.y * t1[5] + r3.x * t1[6] + r3.y * t1[7];
    s1a += __shfl_xor(s1a, 1, 64); s2a += __shfl_xor(s2a, 1, 64);
    s1a += __shfl_xor(s1a, 2, 64); s2a += __shfl_xor(s2a, 2, 64);
    s1a += __shfl_xor(s1a, 4, 64); s2a += __shfl_xor(s2a, 4, 64);
    if (l8 == 0) s12[(size_t)i * Hn + CR * h + t] = make_float2(s1a, s2a);
  }

  // scores: buffer halfword index a'*200 + c (zero address math)
  if (tid < Hn) {
    float acc = 0.f;
    const USH* kp = &kvs[tid];
#pragma unroll
    for (int a = 0; a < 32; a++) acc += qv[a] * bf2f(kp[a * 200]);
    psc[((size_t)i * 4 + h) * Hn + tid] = acc;
  }
}

// ---------------------------------------------------------------------------
// Epilogue: one block per batch row. Fully coalesced — no gathers.
// ---------------------------------------------------------------------------
__global__ __launch_bounds__(256, 8) void ep_kernel(
    const int* __restrict__ history, const int* __restrict__ target,
    const float* __restrict__ hv, const float* __restrict__ dist_mat,
    const float* __restrict__ g, const float* __restrict__ psc,
    const float2* __restrict__ s12, float* __restrict__ out) {
  __shared__ float red[8];
  int i = blockIdx.x, tid = threadIdx.x, lane = tid & 63, wave = tid >> 6;
  int tgt_i = target[i];

  float ea = 0.f; float2 sv = make_float2(0.f, 0.f);
  if (tid < Hn) {
    const float* pp = psc + (size_t)i * 4 * Hn + tid;
    float s = (pp[0] + pp[Hn]) + (pp[2 * Hn] + pp[3 * Hn]);
    sv = s12[(size_t)i * Hn + tid];
    ea = (history[(size_t)i * Hn + tid] != tgt_i) ? __expf(s) : 0.f;
  }
  float wsum = ea;
  for (int off = 32; off > 0; off >>= 1) wsum += __shfl_down(wsum, off, 64);
  if (lane == 0) red[wave] = wsum;
  __syncthreads();
  float esum = red[0] + red[1] + red[2] + red[3];
  float inv = esum > 0.f ? 1.f / sqrtf(esum) : 0.f;  // exp_sum ** 0.5 (BETA)

  float part = 0.f;
  if (tid < Hn) {
    float gc = g[tid]; gc = gc > 0.f ? gc : 0.f;  // relu
    float dm = dist_mat[(size_t)i * Hn + tid];
    float geo = __expf(-dm / (gc + 1.f));
    part = (ea * inv + geo) * sv.x + hv[tid] * sv.y;
  }
  __syncthreads();  // protect red[] reuse
  for (int off = 32; off > 0; off >>= 1) part += __shfl_down(part, off, 64);
  if (lane == 0) red[wave] = part;
  __syncthreads();
  if (tid == 0) {
    float pred = red[0] + red[1] + red[2] + red[3];
    out[i] = 1.f / (1.f + __expf(-pred));
  }
}

extern "C" void kernel_launch(void* const* d_in, const int* in_sizes, int n_in,
                              void* d_out, int out_size, void* d_ws, size_t ws_size,
                              hipStream_t stream) {
  const int*   history = (const int*)d_in[0];
  const int*   target  = (const int*)d_in[1];
  const int*   hregion = (const int*)d_in[2];
  const int*   tregion = (const int*)d_in[3];
  const float* hv      = (const float*)d_in[4];
  const float* dist    = (const float*)d_in[5];
  const int*   uid     = (const int*)d_in[6];
  const float* Et      = (const float*)d_in[7];
  const float* Er      = (const float*)d_in[8];
  const float* Edist   = (const float*)d_in[9];
  const float* Wq      = (const float*)d_in[10];
  const float* Wk      = (const float*)d_in[11];
  const float* Wv      = (const float*)d_in[12];

  char* w = (char*)d_ws;
  float* g   = (float*)w;                            // 1KB slot
  USH*   Af  = (USH*)(w + 1024);                     // 50000*192 bf16 = 19.2MB
  USH*   Bf  = Af + (size_t)NITEM * AFS;             // 1000*192 bf16 = 384KB
  float* qvt = (float*)(Bf + (size_t)NREG * AFS);    // 1024*128 f32 = 512KB
  float* uvt = qvt + (size_t)Bn * Dn;                // 512KB
  float* psc = uvt + (size_t)Bn * Dn;                // 1024*4*200 f32 = 3.2MB
  float2* s12 = (float2*)(psc + (size_t)Bn * 4 * Hn);// 1024*200 float2 = 1.6MB
  float* out = (float*)d_out;

  hipMemsetAsync(g, 0, Hn * sizeof(float), stream);
  ab_kernel<<<AB_TOT + QU_BLOCKS + G_BLOCKS, 256, 0, stream>>>(
      Et, Er, Wk, Wq, Wv, target, tregion, hregion, Edist, uid,
      Af, Bf, qvt, uvt, g);
  sc_kernel<<<Bn * 4, 256, 0, stream>>>(history, target, hregion, tregion,
                                        Et, Er, qvt, uvt, Af, Bf, psc, s12);
  ep_kernel<<<Bn, 256, 0, stream>>>(history, target, hv, dist, g, psc, s12, out);
}

// Round 3
// 153.305 us; speedup vs baseline: 1.0226x; 1.0208x over previous
//
#include <hip/hip_runtime.h>

typedef unsigned short USH;
typedef unsigned int   UIN;
typedef unsigned char  UCH;

static constexpr int Bn = 1024;    // batch
static constexpr int Hn = 200;     // history length
static constexpr int Dn = 128;     // embed/hidden
static constexpr int Dh = 64;      // half embed
static constexpr int NITEM = 50000;
static constexpr int NREG  = 1000;
static constexpr int MT = 64;      // items per ab block
static constexpr int AB_A_BLOCKS = (NITEM + MT - 1) / MT;  // 782
static constexpr int AB_B_BLOCKS = (NREG  + MT - 1) / MT;  // 16
static constexpr int AB_TOT = AB_A_BLOCKS + AB_B_BLOCKS;   // 798
static constexpr int QU_BLOCKS = Bn / 4;                   // 256 (4 rows/block)
static constexpr int G_BLOCKS  = Bn / 16;                  // 64  (16 rows/block)
static constexpr int WTS = 132;    // wt stride (floats)
static constexpr int ETS = 69;     // et stride (floats)
static constexpr int CR  = 50;     // kv rows per chunk (32*200 == 50*128)

// fp8 tables: proj row = 128 B (line-aligned), raw row = 64 B.
// Values scaled by FSCALE before encode; consumers fold in 1/FSCALE.
static constexpr float FSCALE = 128.f;
static constexpr float FINV   = 1.f / 128.f;

__device__ __forceinline__ float bf2f(USH u) {
  return __uint_as_float(((UIN)u) << 16);
}
__device__ __forceinline__ USH f2b(float f) {  // fp32 -> bf16 rne
  UIN x = __float_as_uint(f);
  return (USH)((x + 0x7fffu + ((x >> 16) & 1u)) >> 16);
}
__device__ __forceinline__ UIN enc4(float a, float b, float c, float d) {
  // 4 fp32 -> 4 fp8 e4m3 packed in one dword (hw cvt, RNE+sat)
  int w = __builtin_amdgcn_cvt_pk_fp8_f32(a, b, 0, false);
  w = __builtin_amdgcn_cvt_pk_fp8_f32(c, d, w, true);
  return (UIN)w;
}
__device__ __forceinline__ void dec4(UIN w, float* o) {  // 4 fp8 -> 4 fp32
  auto lo = __builtin_amdgcn_cvt_pk_f32_fp8((int)w, false);
  auto hi = __builtin_amdgcn_cvt_pk_f32_fp8((int)w, true);
  o[0] = lo[0]; o[1] = lo[1]; o[2] = hi[0]; o[3] = hi[1];
}

// ---------------------------------------------------------------------------
// ab_kernel grid = [table GEMM | qv/uv precompute | g accumulate]
//   Ap[item][0:128] = fp8(FSCALE * Et[item].Wk[:,0:64]^T); Ar[item][0:64] = fp8(FSCALE*Et)
//   Bp/Br likewise for regions (Wk[:,64:128], Er).
//   qvt[i][j] = (1/sqrt128) dot(Wq[j], tgtE_i);  uvt[i][d] = sum_j Wv[j][d] tgtE_i[j]
//   g[c] += sum_i row[tr[i]]*row[hr[i,c]]  (row = embed_dist[uid]; g pre-zeroed)
// ---------------------------------------------------------------------------
__global__ __launch_bounds__(256, 2) void ab_kernel(
    const float* __restrict__ Et, const float* __restrict__ Er,
    const float* __restrict__ Wk, const float* __restrict__ Wq,
    const float* __restrict__ Wv, const int* __restrict__ target,
    const int* __restrict__ tregion, const int* __restrict__ hregion,
    const float* __restrict__ embed_dist, const int* __restrict__ uid,
    UCH* __restrict__ Ap, UCH* __restrict__ Bp,
    UCH* __restrict__ Ar, UCH* __restrict__ Br,
    float* __restrict__ qvt, float* __restrict__ uvt, float* __restrict__ g) {
  __shared__ float wt[64 * WTS];  // 33.8KB (qu path reuses as te[4][128])
  __shared__ float et[MT * ETS];  // 17.7KB
  int blk = blockIdx.x, tid = threadIdx.x;

  if (blk >= AB_TOT + QU_BLOCKS) {
    // ---------------- g-accumulate path (64 blocks x 16 rows) ----------------
    int c = tid;
    const float* row = embed_dist + (size_t)uid[0] * NREG;  // 4KB, L1-resident
    float acc = 0.f;
    int ibase = (blk - AB_TOT - QU_BLOCKS) * 16;
    for (int ii = 0; ii < 16; ii++) {
      int i = ibase + ii;
      float td = row[tregion[i]];             // wave-uniform broadcast
      if (c < Hn) acc += td * row[hregion[(size_t)i * Hn + c]];
    }
    if (c < Hn) atomicAdd(&g[c], acc);
    return;
  }

  if (blk >= AB_TOT) {
    // ---------------- qv/uv precompute path ----------------
    float* te = wt;  // te[ii*128 + d], 4 target-embed rows
    int i0 = (blk - AB_TOT) * 4;
#pragma unroll
    for (int v = 0; v < 2; v++) {
      int idx = v * 256 + tid;      // 0..511
      int ii = idx >> 7, d = idx & 127;
      int it = i0 + ii;
      te[ii * 128 + d] = (d < 64) ? Et[(size_t)target[it] * Dh + d]
                                  : Er[(size_t)tregion[it] * Dh + (d - 64)];
    }
    __syncthreads();
    int j = tid & 127, half = tid >> 7;
    float a0 = 0.f, a1 = 0.f, a2 = 0.f, a3 = 0.f;
    if (half == 0) {  // qv: thread j owns Wq row j, 4 batch rows at once
      const float* wr = Wq + (size_t)j * Dn;
#pragma unroll 8
      for (int k = 0; k < 128; k++) {
        float w = wr[k];
        a0 += w * te[k]; a1 += w * te[128 + k];
        a2 += w * te[256 + k]; a3 += w * te[384 + k];
      }
      const float s = 0.088388347648318447f;  // 1/sqrt(128)
      qvt[(size_t)(i0 + 0) * Dn + j] = a0 * s;
      qvt[(size_t)(i0 + 1) * Dn + j] = a1 * s;
      qvt[(size_t)(i0 + 2) * Dn + j] = a2 * s;
      qvt[(size_t)(i0 + 3) * Dn + j] = a3 * s;
    } else {          // uv: column sweep, coalesced across d
      int d = j;
#pragma unroll 8
      for (int k = 0; k < 128; k++) {
        float w = Wv[(size_t)k * Dn + d];
        a0 += w * te[k]; a1 += w * te[128 + k];
        a2 += w * te[256 + k]; a3 += w * te[384 + k];
      }
      uvt[(size_t)(i0 + 0) * Dn + d] = a0;
      uvt[(size_t)(i0 + 1) * Dn + d] = a1;
      uvt[(size_t)(i0 + 2) * Dn + d] = a2;
      uvt[(size_t)(i0 + 3) * Dn + d] = a3;
    }
    return;
  }

  // ---------------- fused-table GEMM path ----------------
  const float* E; UCH* OutP; UCH* OutR; int nmax, base, koff;
  if (blk < AB_A_BLOCKS) { E = Et; OutP = Ap; OutR = Ar; nmax = NITEM; base = blk * MT; koff = 0; }
  else { E = Er; OutP = Bp; OutR = Br; nmax = NREG; base = (blk - AB_A_BLOCKS) * MT; koff = 64; }

  // stage Wk transposed
#pragma unroll
  for (int p = 0; p < 8; p++) {
    int idx = p * 256 + tid;
    int row = idx >> 4, c4 = idx & 15;
    float4 w = *reinterpret_cast<const float4*>(Wk + (size_t)row * Dn + koff + c4 * 4);
    wt[(c4 * 4 + 0) * WTS + row] = w.x;
    wt[(c4 * 4 + 1) * WTS + row] = w.y;
    wt[(c4 * 4 + 2) * WTS + row] = w.z;
    wt[(c4 * 4 + 3) * WTS + row] = w.w;
  }
  // stage E rows row-major
#pragma unroll
  for (int p = 0; p < 4; p++) {
    int idx = p * 256 + tid;
    int m = idx >> 4, c4 = idx & 15;
    int gi = base + m;
    float4 e = make_float4(0.f, 0.f, 0.f, 0.f);
    if (gi < nmax) e = *reinterpret_cast<const float4*>(E + (size_t)gi * Dh + c4 * 4);
    et[m * ETS + c4 * 4 + 0] = e.x;
    et[m * ETS + c4 * 4 + 1] = e.y;
    et[m * ETS + c4 * 4 + 2] = e.z;
    et[m * ETS + c4 * 4 + 3] = e.w;
  }
  __syncthreads();

  // raw-half emit: OutR[item][4*wr..] = fp8(FSCALE * E row), 1024 dwords/block
#pragma unroll
  for (int p = 0; p < 4; p++) {
    int idx = p * 256 + tid;       // 0..1023
    int m = idx >> 4, wr = idx & 15;
    int gi = base + m;
    if (gi < nmax) {
      const float* er = &et[m * ETS + wr * 4];
      *reinterpret_cast<UIN*>(OutR + (size_t)gi * 64 + wr * 4) =
          enc4(er[0] * FSCALE, er[1] * FSCALE, er[2] * FSCALE, er[3] * FSCALE);
    }
  }

  int jt = tid & 15, it = tid >> 4;     // 8 j's, 4 items per thread
  const float* wb = wt + jt * 8;
  const float* eb = et + (it * 4) * ETS;
  float c[4][8];
#pragma unroll
  for (int ii = 0; ii < 4; ii++)
#pragma unroll
    for (int jj = 0; jj < 8; jj++) c[ii][jj] = 0.f;

#pragma unroll 2
  for (int k = 0; k < 64; k++) {
    float4 w0 = *reinterpret_cast<const float4*>(wb + (size_t)k * WTS);
    float4 w1 = *reinterpret_cast<const float4*>(wb + (size_t)k * WTS + 4);
    float e0 = eb[k], e1 = eb[ETS + k], e2 = eb[2 * ETS + k], e3 = eb[3 * ETS + k];
    c[0][0] += e0 * w0.x; c[0][1] += e0 * w0.y; c[0][2] += e0 * w0.z; c[0][3] += e0 * w0.w;
    c[0][4] += e0 * w1.x; c[0][5] += e0 * w1.y; c[0][6] += e0 * w1.z; c[0][7] += e0 * w1.w;
    c[1][0] += e1 * w0.x; c[1][1] += e1 * w0.y; c[1][2] += e1 * w0.z; c[1][3] += e1 * w0.w;
    c[1][4] += e1 * w1.x; c[1][5] += e1 * w1.y; c[1][6] += e1 * w1.z; c[1][7] += e1 * w1.w;
    c[2][0] += e2 * w0.x; c[2][1] += e2 * w0.y; c[2][2] += e2 * w0.z; c[2][3] += e2 * w0.w;
    c[2][4] += e2 * w1.x; c[2][5] += e2 * w1.y; c[2][6] += e2 * w1.z; c[2][7] += e2 * w1.w;
    c[3][0] += e3 * w0.x; c[3][1] += e3 * w0.y; c[3][2] += e3 * w0.z; c[3][3] += e3 * w0.w;
    c[3][4] += e3 * w1.x; c[3][5] += e3 * w1.y; c[3][6] += e3 * w1.z; c[3][7] += e3 * w1.w;
  }

#pragma unroll
  for (int ii = 0; ii < 4; ii++) {
    int item = base + it * 4 + ii;
    if (item < nmax) {
      uint2 pk;
      pk.x = enc4(c[ii][0] * FSCALE, c[ii][1] * FSCALE, c[ii][2] * FSCALE, c[ii][3] * FSCALE);
      pk.y = enc4(c[ii][4] * FSCALE, c[ii][5] * FSCALE, c[ii][6] * FSCALE, c[ii][7] * FSCALE);
      *reinterpret_cast<uint2*>(OutP + (size_t)item * 128 + jt * 8) = pk;
    }
  }
}

// ---------------------------------------------------------------------------
// Partial scores + s1/s2: 4096 blocks = (batch i) x (chunk h of 4).
// v14: fp8 tables — per history item gather 128B proj (Ap) + 64B raw (Ar)
// instead of 384B bf16. qv/uvf/tgtE pre-scaled by 1/FSCALE to fold out the
// fp8 encode scale. kvs stays bf16 (carries xFSCALE).
// ---------------------------------------------------------------------------
__global__ __launch_bounds__(256, 6) void sc_kernel(
    const int* __restrict__ history, const int* __restrict__ target,
    const int* __restrict__ hregion, const int* __restrict__ tregion,
    const float* __restrict__ Et, const float* __restrict__ Er,
    const float* __restrict__ qvt, const float* __restrict__ uvt,
    const UCH* __restrict__ Ap, const UCH* __restrict__ Bp,
    const UCH* __restrict__ Ar, const UCH* __restrict__ Br,
    float* __restrict__ psc, float2* __restrict__ s12) {
  __shared__ USH kvs[CR * Dn];      // 12800B
  __shared__ float tgtE[128], uvf[128], qv[32];
  int b = blockIdx.x, i = b >> 2, h = b & 3;
  int tid = threadIdx.x;
  const int* hrow = history + (size_t)i * Hn + CR * h;
  const int* rrow = hregion + (size_t)i * Hn + CR * h;

  if (tid < 128) {
    tgtE[tid] = FINV * ((tid < 64) ? Et[(size_t)target[i] * Dh + tid]
                                   : Er[(size_t)tregion[i] * Dh + (tid - 64)]);
  } else {
    uvf[tid - 128] = FINV * uvt[(size_t)i * Dn + (tid - 128)];
  }
  if (tid < 32) qv[tid] = FINV * qvt[(size_t)i * Dn + 32 * h + tid];

  // stage kv halves: 16 lanes x 8B (8 fp8) per row; decode+add+pack bf16
  {
    int rlane = tid & 15, rgrp = tid >> 4;
#pragma unroll
    for (int p = 0; p < 4; p++) {
      int t = p * 16 + rgrp;
      if (t < CR) {
        int ia = hrow[t], ib = rrow[t];
        uint2 av = *reinterpret_cast<const uint2*>(Ap + (size_t)ia * 128 + rlane * 8);
        uint2 bv = *reinterpret_cast<const uint2*>(Bp + (size_t)ib * 128 + rlane * 8);
        float fa[8], fb[8];
        dec4(av.x, fa); dec4(av.y, fa + 4);
        dec4(bv.x, fb); dec4(bv.y, fb + 4);
        uint4 pk;
        pk.x = (UIN)f2b(fa[0] + fb[0]) | ((UIN)f2b(fa[1] + fb[1]) << 16);
        pk.y = (UIN)f2b(fa[2] + fb[2]) | ((UIN)f2b(fa[3] + fb[3]) << 16);
        pk.z = (UIN)f2b(fa[4] + fb[4]) | ((UIN)f2b(fa[5] + fb[5]) << 16);
        pk.w = (UIN)f2b(fa[6] + fb[6]) | ((UIN)f2b(fa[7] + fb[7]) << 16);
        *reinterpret_cast<uint4*>(&kvs[t * Dn + rlane * 8]) = pk;
      }
    }
  }

  // prefetch raw halves into registers (no LDS dependency -> before barrier)
  int l8 = tid & 7, r8 = tid >> 3;     // 8 lanes/row, rows r8 and 32+r8
  int ta = r8, tb = 32 + r8;
  bool hasb = (tb < CR);
  uint2 ea, ra, eb2, rb2;
  {
    int iaa = hrow[ta], iba = rrow[ta];
    ea = *reinterpret_cast<const uint2*>(Ar + (size_t)iaa * 64 + l8 * 8);
    ra = *reinterpret_cast<const uint2*>(Br + (size_t)iba * 64 + l8 * 8);
    if (hasb) {
      int iab = hrow[tb], ibb = rrow[tb];
      eb2 = *reinterpret_cast<const uint2*>(Ar + (size_t)iab * 64 + l8 * 8);
      rb2 = *reinterpret_cast<const uint2*>(Br + (size_t)ibb * 64 + l8 * 8);
    }
  }
  __syncthreads();  // kvs + tgtE/uvf/qv ready

  // raw dots from prefetched registers
#pragma unroll
  for (int pass = 0; pass < 2; pass++) {
    if (pass == 1 && !hasb) break;
    uint2 e = (pass == 0) ? ea : eb2;
    uint2 r = (pass == 0) ? ra : rb2;
    int t = (pass == 0) ? ta : tb;
    float fe[8], fr[8];
    dec4(e.x, fe); dec4(e.y, fe + 4);
    dec4(r.x, fr); dec4(r.y, fr + 4);
    const float* u0 = &uvf[l8 * 8];       const float* t0 = &tgtE[l8 * 8];
    const float* u1 = &uvf[64 + l8 * 8];  const float* t1 = &tgtE[64 + l8 * 8];
    float s1a = fe[0] * u0[0] + fe[1] * u0[1] + fe[2] * u0[2] + fe[3] * u0[3]
              + fe[4] * u0[4] + fe[5] * u0[5] + fe[6] * u0[6] + fe[7] * u0[7]
              + fr[0] * u1[0] + fr[1] * u1[1] + fr[2] * u1[2] + fr[3] * u1[3]
              + fr[4] * u1[4] + fr[5] * u1[5] + fr[6] * u1[6] + fr[7] * u1[7];
    float s2a = fe[0] * t0[0] + fe[1] * t0[1] + fe[2] * t0[2] + fe[3] * t0[3]
              + fe[4] * t0[4] + fe[5] * t0[5] + fe[6] * t0[6] + fe[7] * t0[7]
              + fr[0] * t1[0] + fr[1] * t1[1] + fr[2] * t1[2] + fr[3] * t1[3]
              + fr[4] * t1[4] + fr[5] * t1[5] + fr[6] * t1[6] + fr[7] * t1[7];
    s1a += __shfl_xor(s1a, 1, 64); s2a += __shfl_xor(s2a, 1, 64);
    s1a += __shfl_xor(s1a, 2, 64); s2a += __shfl_xor(s2a, 2, 64);
    s1a += __shfl_xor(s1a, 4, 64); s2a += __shfl_xor(s2a, 4, 64);
    if (l8 == 0) s12[(size_t)i * Hn + CR * h + t] = make_float2(s1a, s2a);
  }

  // scores: buffer halfword index a'*200 + c (zero address math)
  if (tid < Hn) {
    float acc = 0.f;
    const USH* kp = &kvs[tid];
#pragma unroll
    for (int a = 0; a < 32; a++) acc += qv[a] * bf2f(kp[a * 200]);
    psc[((size_t)i * 4 + h) * Hn + tid] = acc;
  }
}

// ---------------------------------------------------------------------------
// Epilogue: one block per batch row. Fully coalesced — no gathers.
// ---------------------------------------------------------------------------
__global__ __launch_bounds__(256, 8) void ep_kernel(
    const int* __restrict__ history, const int* __restrict__ target,
    const float* __restrict__ hv, const float* __restrict__ dist_mat,
    const float* __restrict__ g, const float* __restrict__ psc,
    const float2* __restrict__ s12, float* __restrict__ out) {
  __shared__ float red[8];
  int i = blockIdx.x, tid = threadIdx.x, lane = tid & 63, wave = tid >> 6;
  int tgt_i = target[i];

  float ea = 0.f; float2 sv = make_float2(0.f, 0.f);
  if (tid < Hn) {
    const float* pp = psc + (size_t)i * 4 * Hn + tid;
    float s = (pp[0] + pp[Hn]) + (pp[2 * Hn] + pp[3 * Hn]);
    sv = s12[(size_t)i * Hn + tid];
    ea = (history[(size_t)i * Hn + tid] != tgt_i) ? __expf(s) : 0.f;
  }
  float wsum = ea;
  for (int off = 32; off > 0; off >>= 1) wsum += __shfl_down(wsum, off, 64);
  if (lane == 0) red[wave] = wsum;
  __syncthreads();
  float esum = red[0] + red[1] + red[2] + red[3];
  float inv = esum > 0.f ? 1.f / sqrtf(esum) : 0.f;  // exp_sum ** 0.5 (BETA)

  float part = 0.f;
  if (tid < Hn) {
    float gc = g[tid]; gc = gc > 0.f ? gc : 0.f;  // relu
    float dm = dist_mat[(size_t)i * Hn + tid];
    float geo = __expf(-dm / (gc + 1.f));
    part = (ea * inv + geo) * sv.x + hv[tid] * sv.y;
  }
  __syncthreads();  // protect red[] reuse
  for (int off = 32; off > 0; off >>= 1) part += __shfl_down(part, off, 64);
  if (lane == 0) red[wave] = part;
  __syncthreads();
  if (tid == 0) {
    float pred = red[0] + red[1] + red[2] + red[3];
    out[i] = 1.f / (1.f + __expf(-pred));
  }
}

extern "C" void kernel_launch(void* const* d_in, const int* in_sizes, int n_in,
                              void* d_out, int out_size, void* d_ws, size_t ws_size,
                              hipStream_t stream) {
  const int*   history = (const int*)d_in[0];
  const int*   target  = (const int*)d_in[1];
  const int*   hregion = (const int*)d_in[2];
  const int*   tregion = (const int*)d_in[3];
  const float* hv      = (const float*)d_in[4];
  const float* dist    = (const float*)d_in[5];
  const int*   uid     = (const int*)d_in[6];
  const float* Et      = (const float*)d_in[7];
  const float* Er      = (const float*)d_in[8];
  const float* Edist   = (const float*)d_in[9];
  const float* Wq      = (const float*)d_in[10];
  const float* Wk      = (const float*)d_in[11];
  const float* Wv      = (const float*)d_in[12];

  char* w = (char*)d_ws;
  float* g   = (float*)w;                            // 1KB slot
  UCH*   Ap  = (UCH*)(w + 1024);                     // 50000*128 B = 6.4MB
  UCH*   Bp  = Ap + (size_t)NITEM * 128;             // 1000*128 B = 128KB
  UCH*   Ar  = Bp + (size_t)NREG * 128;              // 50000*64 B = 3.2MB
  UCH*   Br  = Ar + (size_t)NITEM * 64;              // 1000*64 B = 64KB
  float* qvt = (float*)(Br + (size_t)NREG * 64);     // 1024*128 f32 = 512KB
  float* uvt = qvt + (size_t)Bn * Dn;                // 512KB
  float* psc = uvt + (size_t)Bn * Dn;                // 1024*4*200 f32 = 3.2MB
  float2* s12 = (float2*)(psc + (size_t)Bn * 4 * Hn);// 1024*200 float2 = 1.6MB
  float* out = (float*)d_out;

  hipMemsetAsync(g, 0, Hn * sizeof(float), stream);
  ab_kernel<<<AB_TOT + QU_BLOCKS + G_BLOCKS, 256, 0, stream>>>(
      Et, Er, Wk, Wq, Wv, target, tregion, hregion, Edist, uid,
      Ap, Bp, Ar, Br, qvt, uvt, g);
  sc_kernel<<<Bn * 4, 256, 0, stream>>>(history, target, hregion, tregion,
                                        Et, Er, qvt, uvt, Ap, Bp, Ar, Br, psc, s12);
  ep_kernel<<<Bn, 256, 0, stream>>>(history, target, hv, dist, g, psc, s12, out);
}

// Round 5
// 152.198 us; speedup vs baseline: 1.0300x; 1.0073x over previous
//
#include <hip/hip_runtime.h>

typedef unsigned short USH;
typedef unsigned int   UIN;
typedef unsigned char  UCH;

static constexpr int Bn = 1024;    // batch
static constexpr int Hn = 200;     // history length
static constexpr int Dn = 128;     // embed/hidden
static constexpr int Dh = 64;      // half embed
static constexpr int NITEM = 50000;
static constexpr int NREG  = 1000;
static constexpr int MT = 64;      // items per ab block
static constexpr int AB_A_BLOCKS = (NITEM + MT - 1) / MT;  // 782
static constexpr int AB_B_BLOCKS = (NREG  + MT - 1) / MT;  // 16
static constexpr int AB_TOT = AB_A_BLOCKS + AB_B_BLOCKS;   // 798
static constexpr int QU_BLOCKS = Bn / 4;                   // 256 (4 rows/block)
static constexpr int G_BLOCKS  = Bn / 16;                  // 64  (16 rows/block)
static constexpr int WTS = 132;    // wt stride (floats)
static constexpr int ETS = 69;     // et stride (floats)
static constexpr int CR  = 50;     // kv rows per chunk (32*200 == 50*128)
static constexpr int RS  = 192;    // fused fp8 row stride: 128 proj + 64 raw

// fp8 tables scaled by FSCALE before encode; consumers fold in 1/FSCALE.
static constexpr float FSCALE = 128.f;
static constexpr float FINV   = 1.f / 128.f;

__device__ __forceinline__ float bf2f(USH u) {
  return __uint_as_float(((UIN)u) << 16);
}
__device__ __forceinline__ USH f2b(float f) {  // fp32 -> bf16 rne
  UIN x = __float_as_uint(f);
  return (USH)((x + 0x7fffu + ((x >> 16) & 1u)) >> 16);
}
__device__ __forceinline__ UIN enc4(float a, float b, float c, float d) {
  // 4 fp32 -> 4 fp8 e4m3 packed in one dword (hw cvt, RNE+sat)
  int w = __builtin_amdgcn_cvt_pk_fp8_f32(a, b, 0, false);
  w = __builtin_amdgcn_cvt_pk_fp8_f32(c, d, w, true);
  return (UIN)w;
}
__device__ __forceinline__ void dec4(UIN w, float* o) {  // 4 fp8 -> 4 fp32
  auto lo = __builtin_amdgcn_cvt_pk_f32_fp8((int)w, false);
  auto hi = __builtin_amdgcn_cvt_pk_f32_fp8((int)w, true);
  o[0] = lo[0]; o[1] = lo[1]; o[2] = hi[0]; o[3] = hi[1];
}

// ---------------------------------------------------------------------------
// ab_kernel grid = [table GEMM | qv/uv precompute | g accumulate]
//   Cf[item][0:128]  = fp8(FSCALE * Et[item].Wk[:,0:64]^T)
//   Cf[item][128:192]= fp8(FSCALE * Et[item])          (raw half)
//   Df[reg] likewise (Wk[:,64:128], Er).  Row stride RS=192B -> 2 lines/row.
//   qvt[i][j] = (1/sqrt128) dot(Wq[j], tgtE_i);  uvt[i][d] = sum_j Wv[j][d] tgtE_i[j]
//   g[c] += sum_i row[tr[i]]*row[hr[i,c]]  (row = embed_dist[uid]; g pre-zeroed)
// ---------------------------------------------------------------------------
__global__ __launch_bounds__(256, 2) void ab_kernel(
    const float* __restrict__ Et, const float* __restrict__ Er,
    const float* __restrict__ Wk, const float* __restrict__ Wq,
    const float* __restrict__ Wv, const int* __restrict__ target,
    const int* __restrict__ tregion, const int* __restrict__ hregion,
    const float* __restrict__ embed_dist, const int* __restrict__ uid,
    UCH* __restrict__ Cf, UCH* __restrict__ Df,
    float* __restrict__ qvt, float* __restrict__ uvt, float* __restrict__ g) {
  __shared__ float wt[64 * WTS];  // 33.8KB (qu path reuses as te[4][128])
  __shared__ float et[MT * ETS];  // 17.7KB
  int blk = blockIdx.x, tid = threadIdx.x;

  if (blk >= AB_TOT + QU_BLOCKS) {
    // ---------------- g-accumulate path (64 blocks x 16 rows) ----------------
    int c = tid;
    const float* row = embed_dist + (size_t)uid[0] * NREG;  // 4KB, L1-resident
    float acc = 0.f;
    int ibase = (blk - AB_TOT - QU_BLOCKS) * 16;
    for (int ii = 0; ii < 16; ii++) {
      int i = ibase + ii;
      float td = row[tregion[i]];             // wave-uniform broadcast
      if (c < Hn) acc += td * row[hregion[(size_t)i * Hn + c]];
    }
    if (c < Hn) atomicAdd(&g[c], acc);
    return;
  }

  if (blk >= AB_TOT) {
    // ---------------- qv/uv precompute path ----------------
    float* te = wt;  // te[ii*128 + d], 4 target-embed rows
    int i0 = (blk - AB_TOT) * 4;
#pragma unroll
    for (int v = 0; v < 2; v++) {
      int idx = v * 256 + tid;      // 0..511
      int ii = idx >> 7, d = idx & 127;
      int it = i0 + ii;
      te[ii * 128 + d] = (d < 64) ? Et[(size_t)target[it] * Dh + d]
                                  : Er[(size_t)tregion[it] * Dh + (d - 64)];
    }
    __syncthreads();
    int j = tid & 127, half = tid >> 7;
    float a0 = 0.f, a1 = 0.f, a2 = 0.f, a3 = 0.f;
    if (half == 0) {  // qv: thread j owns Wq row j, 4 batch rows at once
      const float* wr = Wq + (size_t)j * Dn;
#pragma unroll 8
      for (int k = 0; k < 128; k++) {
        float w = wr[k];
        a0 += w * te[k]; a1 += w * te[128 + k];
        a2 += w * te[256 + k]; a3 += w * te[384 + k];
      }
      const float s = 0.088388347648318447f;  // 1/sqrt(128)
      qvt[(size_t)(i0 + 0) * Dn + j] = a0 * s;
      qvt[(size_t)(i0 + 1) * Dn + j] = a1 * s;
      qvt[(size_t)(i0 + 2) * Dn + j] = a2 * s;
      qvt[(size_t)(i0 + 3) * Dn + j] = a3 * s;
    } else {          // uv: column sweep, coalesced across d
      int d = j;
#pragma unroll 8
      for (int k = 0; k < 128; k++) {
        float w = Wv[(size_t)k * Dn + d];
        a0 += w * te[k]; a1 += w * te[128 + k];
        a2 += w * te[256 + k]; a3 += w * te[384 + k];
      }
      uvt[(size_t)(i0 + 0) * Dn + d] = a0;
      uvt[(size_t)(i0 + 1) * Dn + d] = a1;
      uvt[(size_t)(i0 + 2) * Dn + d] = a2;
      uvt[(size_t)(i0 + 3) * Dn + d] = a3;
    }
    return;
  }

  // ---------------- fused-table GEMM path ----------------
  const float* E; UCH* OutT; int nmax, base, koff;
  if (blk < AB_A_BLOCKS) { E = Et; OutT = Cf; nmax = NITEM; base = blk * MT; koff = 0; }
  else { E = Er; OutT = Df; nmax = NREG; base = (blk - AB_A_BLOCKS) * MT; koff = 64; }

  // stage Wk transposed
#pragma unroll
  for (int p = 0; p < 8; p++) {
    int idx = p * 256 + tid;
    int row = idx >> 4, c4 = idx & 15;
    float4 w = *reinterpret_cast<const float4*>(Wk + (size_t)row * Dn + koff + c4 * 4);
    wt[(c4 * 4 + 0) * WTS + row] = w.x;
    wt[(c4 * 4 + 1) * WTS + row] = w.y;
    wt[(c4 * 4 + 2) * WTS + row] = w.z;
    wt[(c4 * 4 + 3) * WTS + row] = w.w;
  }
  // stage E rows row-major
#pragma unroll
  for (int p = 0; p < 4; p++) {
    int idx = p * 256 + tid;
    int m = idx >> 4, c4 = idx & 15;
    int gi = base + m;
    float4 e = make_float4(0.f, 0.f, 0.f, 0.f);
    if (gi < nmax) e = *reinterpret_cast<const float4*>(E + (size_t)gi * Dh + c4 * 4);
    et[m * ETS + c4 * 4 + 0] = e.x;
    et[m * ETS + c4 * 4 + 1] = e.y;
    et[m * ETS + c4 * 4 + 2] = e.z;
    et[m * ETS + c4 * 4 + 3] = e.w;
  }
  __syncthreads();

  // raw-half emit: Cf[item][128 + 4wr..] = fp8(FSCALE * E row)
#pragma unroll
  for (int p = 0; p < 4; p++) {
    int idx = p * 256 + tid;       // 0..1023
    int m = idx >> 4, wr = idx & 15;
    int gi = base + m;
    if (gi < nmax) {
      const float* er = &et[m * ETS + wr * 4];
      *reinterpret_cast<UIN*>(OutT + (size_t)gi * RS + 128 + wr * 4) =
          enc4(er[0] * FSCALE, er[1] * FSCALE, er[2] * FSCALE, er[3] * FSCALE);
    }
  }

  int jt = tid & 15, it = tid >> 4;     // 8 j's, 4 items per thread
  const float* wb = wt + jt * 8;
  const float* eb = et + (it * 4) * ETS;
  float c[4][8];
#pragma unroll
  for (int ii = 0; ii < 4; ii++)
#pragma unroll
    for (int jj = 0; jj < 8; jj++) c[ii][jj] = 0.f;

#pragma unroll 2
  for (int k = 0; k < 64; k++) {
    float4 w0 = *reinterpret_cast<const float4*>(wb + (size_t)k * WTS);
    float4 w1 = *reinterpret_cast<const float4*>(wb + (size_t)k * WTS + 4);
    float e0 = eb[k], e1 = eb[ETS + k], e2 = eb[2 * ETS + k], e3 = eb[3 * ETS + k];
    c[0][0] += e0 * w0.x; c[0][1] += e0 * w0.y; c[0][2] += e0 * w0.z; c[0][3] += e0 * w0.w;
    c[0][4] += e0 * w1.x; c[0][5] += e0 * w1.y; c[0][6] += e0 * w1.z; c[0][7] += e0 * w1.w;
    c[1][0] += e1 * w0.x; c[1][1] += e1 * w0.y; c[1][2] += e1 * w0.z; c[1][3] += e1 * w0.w;
    c[1][4] += e1 * w1.x; c[1][5] += e1 * w1.y; c[1][6] += e1 * w1.z; c[1][7] += e1 * w1.w;
    c[2][0] += e2 * w0.x; c[2][1] += e2 * w0.y; c[2][2] += e2 * w0.z; c[2][3] += e2 * w0.w;
    c[2][4] += e2 * w1.x; c[2][5] += e2 * w1.y; c[2][6] += e2 * w1.z; c[2][7] += e2 * w1.w;
    c[3][0] += e3 * w0.x; c[3][1] += e3 * w0.y; c[3][2] += e3 * w0.z; c[3][3] += e3 * w0.w;
    c[3][4] += e3 * w1.x; c[3][5] += e3 * w1.y; c[3][6] += e3 * w1.z; c[3][7] += e3 * w1.w;
  }

#pragma unroll
  for (int ii = 0; ii < 4; ii++) {
    int item = base + it * 4 + ii;
    if (item < nmax) {
      uint2 pk;
      pk.x = enc4(c[ii][0] * FSCALE, c[ii][1] * FSCALE, c[ii][2] * FSCALE, c[ii][3] * FSCALE);
      pk.y = enc4(c[ii][4] * FSCALE, c[ii][5] * FSCALE, c[ii][6] * FSCALE, c[ii][7] * FSCALE);
      *reinterpret_cast<uint2*>(OutT + (size_t)item * RS + jt * 8) = pk;
    }
  }
}

// ---------------------------------------------------------------------------
// Partial scores + s1/s2: 4096 blocks = (batch i) x (chunk h of 4).
// v15: request-count attack. Fused 192B rows; all gathers uint4 (16B/lane):
// proj 8 lanes/row, raw 4 lanes/row -> LDS. ~1400 gather requests/block
// (was ~3000). Dots read raw fp8 from LDS post-barrier.
// ---------------------------------------------------------------------------
__global__ __launch_bounds__(256, 6) void sc_kernel(
    const int* __restrict__ history, const int* __restrict__ target,
    const int* __restrict__ hregion, const int* __restrict__ tregion,
    const float* __restrict__ Et, const float* __restrict__ Er,
    const float* __restrict__ qvt, const float* __restrict__ uvt,
    const UCH* __restrict__ Cf, const UCH* __restrict__ Df,
    float* __restrict__ psc, float2* __restrict__ s12) {
  __shared__ USH kvs[CR * Dn];        // 12800B bf16 proj sum (x FSCALE)
  __shared__ uint4 rawA[CR * 4];      // 3200B fp8 item raw rows
  __shared__ uint4 rawB[CR * 4];      // 3200B fp8 region raw rows
  __shared__ float tgtE[128], uvf[128], qv[32];
  int b = blockIdx.x, i = b >> 2, h = b & 3;
  int tid = threadIdx.x;
  const int* hrow = history + (size_t)i * Hn + CR * h;
  const int* rrow = hregion + (size_t)i * Hn + CR * h;

  if (tid < 128) {
    tgtE[tid] = FINV * ((tid < 64) ? Et[(size_t)target[i] * Dh + tid]
                                   : Er[(size_t)tregion[i] * Dh + (tid - 64)]);
  } else {
    uvf[tid - 128] = FINV * uvt[(size_t)i * Dn + (tid - 128)];
  }
  if (tid < 32) qv[tid] = FINV * qvt[(size_t)i * Dn + 32 * h + tid];

  // raw staging: 4 lanes x 16B per row (200 active threads)
  {
    int seg = tid & 3, row = tid >> 2;
    if (row < CR) {
      int ia = hrow[row], ib = rrow[row];
      rawA[row * 4 + seg] = *reinterpret_cast<const uint4*>(Cf + (size_t)ia * RS + 128 + seg * 16);
      rawB[row * 4 + seg] = *reinterpret_cast<const uint4*>(Df + (size_t)ib * RS + 128 + seg * 16);
    }
  }

  // proj staging: 8 lanes x 16B per row; decode fp8, add, pack bf16
#pragma unroll
  for (int p = 0; p < 2; p++) {
    int idx = p * 256 + tid;
    int seg = idx & 7, row = idx >> 3;
    if (row < CR) {
      int ia = hrow[row], ib = rrow[row];
      uint4 av = *reinterpret_cast<const uint4*>(Cf + (size_t)ia * RS + seg * 16);
      uint4 bv = *reinterpret_cast<const uint4*>(Df + (size_t)ib * RS + seg * 16);
      float fa[16], fb[16];
      dec4(av.x, fa);      dec4(av.y, fa + 4);  dec4(av.z, fa + 8);  dec4(av.w, fa + 12);
      dec4(bv.x, fb);      dec4(bv.y, fb + 4);  dec4(bv.z, fb + 8);  dec4(bv.w, fb + 12);
      uint4 k0, k1;
      k0.x = (UIN)f2b(fa[0] + fb[0])  | ((UIN)f2b(fa[1] + fb[1]) << 16);
      k0.y = (UIN)f2b(fa[2] + fb[2])  | ((UIN)f2b(fa[3] + fb[3]) << 16);
      k0.z = (UIN)f2b(fa[4] + fb[4])  | ((UIN)f2b(fa[5] + fb[5]) << 16);
      k0.w = (UIN)f2b(fa[6] + fb[6])  | ((UIN)f2b(fa[7] + fb[7]) << 16);
      k1.x = (UIN)f2b(fa[8] + fb[8])  | ((UIN)f2b(fa[9] + fb[9]) << 16);
      k1.y = (UIN)f2b(fa[10] + fb[10]) | ((UIN)f2b(fa[11] + fb[11]) << 16);
      k1.z = (UIN)f2b(fa[12] + fb[12]) | ((UIN)f2b(fa[13] + fb[13]) << 16);
      k1.w = (UIN)f2b(fa[14] + fb[14]) | ((UIN)f2b(fa[15] + fb[15]) << 16);
      *reinterpret_cast<uint4*>(&kvs[row * Dn + seg * 16]) = k0;
      *reinterpret_cast<uint4*>(&kvs[row * Dn + seg * 16 + 8]) = k1;
    }
  }
  __syncthreads();  // kvs + raw + tgtE/uvf/qv ready

  // s1/s2 dots from LDS raw fp8
  int l8 = tid & 7, r8 = tid >> 3;     // 8 lanes/row; rows r8 and 32+r8
#pragma unroll
  for (int pass = 0; pass < 2; pass++) {
    int t = (pass == 0) ? r8 : 32 + r8;
    if (t < CR) {
      uint2 e = *(reinterpret_cast<const uint2*>(&rawA[t * 4]) + l8);
      uint2 r = *(reinterpret_cast<const uint2*>(&rawB[t * 4]) + l8);
      float fe[8], fr[8];
      dec4(e.x, fe); dec4(e.y, fe + 4);
      dec4(r.x, fr); dec4(r.y, fr + 4);
      const float* u0 = &uvf[l8 * 8];       const float* t0 = &tgtE[l8 * 8];
      const float* u1 = &uvf[64 + l8 * 8];  const float* t1 = &tgtE[64 + l8 * 8];
      float s1a = fe[0] * u0[0] + fe[1] * u0[1] + fe[2] * u0[2] + fe[3] * u0[3]
                + fe[4] * u0[4] + fe[5] * u0[5] + fe[6] * u0[6] + fe[7] * u0[7]
                + fr[0] * u1[0] + fr[1] * u1[1] + fr[2] * u1[2] + fr[3] * u1[3]
                + fr[4] * u1[4] + fr[5] * u1[5] + fr[6] * u1[6] + fr[7] * u1[7];
      float s2a = fe[0] * t0[0] + fe[1] * t0[1] + fe[2] * t0[2] + fe[3] * t0[3]
                + fe[4] * t0[4] + fe[5] * t0[5] + fe[6] * t0[6] + fe[7] * t0[7]
                + fr[0] * t1[0] + fr[1] * t1[1] + fr[2] * t1[2] + fr[3] * t1[3]
                + fr[4] * t1[4] + fr[5] * t1[5] + fr[6] * t1[6] + fr[7] * t1[7];
      s1a += __shfl_xor(s1a, 1, 64); s2a += __shfl_xor(s2a, 1, 64);
      s1a += __shfl_xor(s1a, 2, 64); s2a += __shfl_xor(s2a, 2, 64);
      s1a += __shfl_xor(s1a, 4, 64); s2a += __shfl_xor(s2a, 4, 64);
      if (l8 == 0) s12[(size_t)i * Hn + CR * h + t] = make_float2(s1a, s2a);
    }
  }

  // scores: buffer halfword index a'*200 + c (zero address math)
  if (tid < Hn) {
    float acc = 0.f;
    const USH* kp = &kvs[tid];
#pragma unroll
    for (int a = 0; a < 32; a++) acc += qv[a] * bf2f(kp[a * 200]);
    psc[((size_t)i * 4 + h) * Hn + tid] = acc;
  }
}

// ---------------------------------------------------------------------------
// Epilogue: one block per batch row. Fully coalesced — no gathers.
// ---------------------------------------------------------------------------
__global__ __launch_bounds__(256, 8) void ep_kernel(
    const int* __restrict__ history, const int* __restrict__ target,
    const float* __restrict__ hv, const float* __restrict__ dist_mat,
    const float* __restrict__ g, const float* __restrict__ psc,
    const float2* __restrict__ s12, float* __restrict__ out) {
  __shared__ float red[8];
  int i = blockIdx.x, tid = threadIdx.x, lane = tid & 63, wave = tid >> 6;
  int tgt_i = target[i];

  float ea = 0.f; float2 sv = make_float2(0.f, 0.f);
  if (tid < Hn) {
    const float* pp = psc + (size_t)i * 4 * Hn + tid;
    float s = (pp[0] + pp[Hn]) + (pp[2 * Hn] + pp[3 * Hn]);
    sv = s12[(size_t)i * Hn + tid];
    ea = (history[(size_t)i * Hn + tid] != tgt_i) ? __expf(s) : 0.f;
  }
  float wsum = ea;
  for (int off = 32; off > 0; off >>= 1) wsum += __shfl_down(wsum, off, 64);
  if (lane == 0) red[wave] = wsum;
  __syncthreads();
  float esum = red[0] + red[1] + red[2] + red[3];
  float inv = esum > 0.f ? 1.f / sqrtf(esum) : 0.f;  // exp_sum ** 0.5 (BETA)

  float part = 0.f;
  if (tid < Hn) {
    float gc = g[tid]; gc = gc > 0.f ? gc : 0.f;  // relu
    float dm = dist_mat[(size_t)i * Hn + tid];
    float geo = __expf(-dm / (gc + 1.f));
    part = (ea * inv + geo) * sv.x + hv[tid] * sv.y;
  }
  __syncthreads();  // protect red[] reuse
  for (int off = 32; off > 0; off >>= 1) part += __shfl_down(part, off, 64);
  if (lane == 0) red[wave] = part;
  __syncthreads();
  if (tid == 0) {
    float pred = red[0] + red[1] + red[2] + red[3];
    out[i] = 1.f / (1.f + __expf(-pred));
  }
}

extern "C" void kernel_launch(void* const* d_in, const int* in_sizes, int n_in,
                              void* d_out, int out_size, void* d_ws, size_t ws_size,
                              hipStream_t stream) {
  const int*   history = (const int*)d_in[0];
  const int*   target  = (const int*)d_in[1];
  const int*   hregion = (const int*)d_in[2];
  const int*   tregion = (const int*)d_in[3];
  const float* hv      = (const float*)d_in[4];
  const float* dist    = (const float*)d_in[5];
  const int*   uid     = (const int*)d_in[6];
  const float* Et      = (const float*)d_in[7];
  const float* Er      = (const float*)d_in[8];
  const float* Edist   = (const float*)d_in[9];
  const float* Wq      = (const float*)d_in[10];
  const float* Wk      = (const float*)d_in[11];
  const float* Wv      = (const float*)d_in[12];

  char* w = (char*)d_ws;
  float* g   = (float*)w;                            // 1KB slot
  UCH*   Cf  = (UCH*)(w + 1024);                     // 50000*192 B = 9.6MB
  UCH*   Df  = Cf + (size_t)NITEM * RS;              // 1000*192 B = 192KB
  float* qvt = (float*)(Df + (size_t)NREG * RS);     // 1024*128 f32 = 512KB
  float* uvt = qvt + (size_t)Bn * Dn;                // 512KB
  float* psc = uvt + (size_t)Bn * Dn;                // 1024*4*200 f32 = 3.2MB
  float2* s12 = (float2*)(psc + (size_t)Bn * 4 * Hn);// 1024*200 float2 = 1.6MB
  float* out = (float*)d_out;

  hipMemsetAsync(g, 0, Hn * sizeof(float), stream);
  ab_kernel<<<AB_TOT + QU_BLOCKS + G_BLOCKS, 256, 0, stream>>>(
      Et, Er, Wk, Wq, Wv, target, tregion, hregion, Edist, uid,
      Cf, Df, qvt, uvt, g);
  sc_kernel<<<Bn * 4, 256, 0, stream>>>(history, target, hregion, tregion,
                                        Et, Er, qvt, uvt, Cf, Df, psc, s12);
  ep_kernel<<<Bn, 256, 0, stream>>>(history, target, hv, dist, g, psc, s12, out);
}